// Round 1
// baseline (4520.427 us; speedup 1.0000x reference)
//
#include <hip/hip_runtime.h>
#include <math.h>

// Problem constants (fixed by setup_inputs)
#define NB   256      // batch N
#define TT   36       // T
#define FF   50       // F
#define PP   80       // npole
#define KK   161      // K = 1 + 2*npole
#define KSTR 172      // padded LDS/global row stride for A and y (bank-conflict friendly, 16B aligned)
#define CB   50       // columns per block (12800/50 = 256 blocks, 1/CU)
#define CPAD 55       // padded column count per block (CG*CT)
#define KG   23       // k-groups (23*7 = 161 exact)
#define CG   11       // col-groups
#define KT   7        // k per thread
#define CT   5        // cols per thread
#define NITER 100     // FISTA inner iterations
#define LAMB 0.1f

#define CODE_SZ (NB*KK*FF)          // 2,060,800
#define D_OFF   CODE_SZ             // D chunk offset in d_out
#define R_OFF   (CODE_SZ + TT*KK)   // reconst chunk offset

// ws float offsets
#define WSA 64                      // A matrix [KK][KSTR]
#define WSC (64 + KK*KSTR)          // c = DtY * Linv, [12800][KK]

// ---------------------------------------------------------------------------
// K1: build D (also store to d_out), DtD, L = ||DtD||_F, A = I - DtD/L -> ws
__global__ __launch_bounds__(256) void k_build(const float* __restrict__ rr,
                                               const float* __restrict__ th,
                                               float* __restrict__ out,
                                               float* __restrict__ ws) {
    __shared__ float Dl[TT*KK];
    __shared__ float red[256];
    __shared__ float linv_s;
    int tid = threadIdx.x;
    for (int e = tid; e < TT*KK; e += 256) {
        int t = e / KK, k = e % KK;
        float v;
        if (k == 0) v = 1.f;
        else if (k <= PP) { int p = k - 1;     v = powf(rr[p], (float)t) * cosf((float)t * th[p]); }
        else             { int p = k - 1 - PP; v = powf(rr[p], (float)t) * sinf((float)t * th[p]); }
        Dl[e] = v;
        out[D_OFF + e] = v;
    }
    __syncthreads();
    float ssq = 0.f;
    for (int e = tid; e < KK*KK; e += 256) {
        int k1 = e / KK, k2 = e % KK;
        float s = 0.f;
        for (int t = 0; t < TT; ++t) s += Dl[t*KK + k1] * Dl[t*KK + k2];
        ws[WSA + k1*KSTR + k2] = s;      // raw DtD, rescaled below
        ssq += s * s;
    }
    red[tid] = ssq;
    __syncthreads();
    for (int off = 128; off > 0; off >>= 1) {
        if (tid < off) red[tid] += red[tid + off];
        __syncthreads();
    }
    if (tid == 0) {
        float linv = 1.f / sqrtf(red[0]);
        ws[0] = linv;     // Linv
        ws[1] = 0.f;      // zero the wn^2 accumulator (re-poisoned each call)
        linv_s = linv;
    }
    __syncthreads();
    float linv = linv_s;
    for (int e = tid; e < KK*KSTR; e += 256) {
        int k = e / KSTR, j = e % KSTR;
        float v = 0.f;
        if (j < KK) v = (k == j ? 1.f : 0.f) - ws[WSA + e] * linv;
        ws[WSA + e] = v;   // A, zero-padded cols j>=161
    }
}

// ---------------------------------------------------------------------------
// K2: c[col][k] = Linv * sum_t D[t][k] * x[n][t][f],  col = n*FF + f
__global__ __launch_bounds__(256) void k_dty(const float* __restrict__ x,
                                             const float* __restrict__ out_d,
                                             const float* __restrict__ ws,
                                             float* __restrict__ ws_c) {
    __shared__ float Dl[TT*KK];
    __shared__ float xl[TT*FF];
    int n = blockIdx.x, tid = threadIdx.x;
    for (int e = tid; e < TT*KK; e += 256) Dl[e] = out_d[D_OFF + e];
    for (int e = tid; e < TT*FF; e += 256) xl[e] = x[n*TT*FF + e];
    __syncthreads();
    float linv = ws[0];
    for (int e = tid; e < KK*FF; e += 256) {
        int k = e / FF, f = e % FF;
        float s = 0.f;
        for (int t = 0; t < TT; ++t) s += Dl[t*KK + k] * xl[t*FF + f];
        ws_c[(size_t)(n*FF + f)*KK + k] = s * linv;
    }
}

// ---------------------------------------------------------------------------
// K3: full FISTA run (100 iterations) for 50 columns per block, state in LDS/regs.
// phase=0: wl scalar (w==1). phase=1: wl from previous code (in code_out) + norm scalar.
__global__ __launch_bounds__(256, 1) void k_fista(const float* __restrict__ Ag,
                                                  const float* __restrict__ cgl,
                                                  const float* __restrict__ ws,
                                                  float* __restrict__ code_out,
                                                  int phase) {
    __shared__ float As[KK*KSTR];    // 110,768 B
    __shared__ float ys[CPAD*KSTR];  //  37,840 B
    int tid = threadIdx.x;

    // cooperative A load (16B vectors, rows 16B-aligned since KSTR%4==0)
    const float4* Ag4 = (const float4*)Ag;
    float4* As4 = (float4*)As;
    for (int e = tid; e < KK*KSTR/4; e += 256) As4[e] = Ag4[e];
    float4 z4 = make_float4(0.f, 0.f, 0.f, 0.f);
    float4* ys4 = (float4*)ys;
    for (int e = tid; e < CPAD*KSTR/4; e += 256) ys4[e] = z4;

    bool active = tid < KG*CG;           // 253 active, 3 idle (still hit barriers)
    int kg = tid / CG, cg = tid % CG;    // cg fast within wave: A broadcast, y <=2-way
    int k0 = kg * KT, c0 = cg * CT;
    int colbase = blockIdx.x * CB;

    float cm[KT][CT], cp[KT][CT], xo[KT][CT];
    if (active) {
        float linv = ws[0];
        float wl0 = LAMB * linv;
        float fac = 0.f;
        if (phase) fac = (float)KK * LAMB * linv * rsqrtf(ws[1]);
        #pragma unroll
        for (int ci = 0; ci < CT; ++ci) {
            int lc = c0 + ci;
            bool v = lc < CB;
            int col = colbase + lc;
            int n = col / FF, f = col % FF;
            #pragma unroll
            for (int ki = 0; ki < KT; ++ki) {
                int k = k0 + ki;
                float cv = 0.f, wl = 0.f;
                if (v) {
                    cv = cgl[(size_t)col*KK + k];
                    if (phase) {
                        float prev = code_out[(size_t)n*KK*FF + (size_t)k*FF + f];
                        wl = fac / (fabsf(prev) + 0.01f);
                    } else {
                        wl = wl0;
                    }
                }
                cm[ki][ci] = cv - wl;
                cp[ki][ci] = cv + wl;
                xo[ki][ci] = 0.f;
            }
        }
    }
    __syncthreads();

    float t_old = 1.f;
    for (int it = 0; it < NITER; ++it) {
        float acc[KT][CT];
        #pragma unroll
        for (int ki = 0; ki < KT; ++ki)
            #pragma unroll
            for (int ci = 0; ci < CT; ++ci) acc[ki][ci] = 0.f;

        if (active) {
            const float4* Ar = (const float4*)As + k0*(KSTR/4);
            const float4* Yr = (const float4*)ys + c0*(KSTR/4);
            for (int jq = 0; jq < KSTR/4; ++jq) {     // 43 steps; pads are zero
                float4 av[KT], yv[CT];
                #pragma unroll
                for (int ki = 0; ki < KT; ++ki) av[ki] = Ar[ki*(KSTR/4) + jq];
                #pragma unroll
                for (int ci = 0; ci < CT; ++ci) yv[ci] = Yr[ci*(KSTR/4) + jq];
                #pragma unroll
                for (int ki = 0; ki < KT; ++ki)
                    #pragma unroll
                    for (int ci = 0; ci < CT; ++ci) {
                        acc[ki][ci] += av[ki].x*yv[ci].x + av[ki].y*yv[ci].y
                                     + av[ki].z*yv[ci].z + av[ki].w*yv[ci].w;
                    }
            }
        }
        __syncthreads();   // all GEMM reads of ys done before epilogue writes

        float t_new = 0.5f * (1.f + sqrtf(1.f + 4.f*t_old*t_old));
        float beta = (t_old - 1.f) / t_new;
        t_old = t_new;

        if (active) {
            #pragma unroll
            for (int ki = 0; ki < KT; ++ki)
                #pragma unroll
                for (int ci = 0; ci < CT; ++ci) {
                    float ay = acc[ki][ci];
                    float xn = fmaxf(0.f, ay + cm[ki][ci]) + fminf(0.f, ay + cp[ki][ci]);
                    float yn = xn + beta * (xn - xo[ki][ci]);
                    xo[ki][ci] = xn;
                    ys[(c0+ci)*KSTR + (k0+ki)] = yn;   // pad cols stay 0 (c=wl=0 -> ay=0)
                }
        }
        __syncthreads();   // epilogue writes visible before next GEMM
    }

    if (active) {
        #pragma unroll
        for (int ci = 0; ci < CT; ++ci) {
            int lc = c0 + ci;
            if (lc >= CB) continue;
            int col = colbase + lc;
            int n = col / FF, f = col % FF;
            #pragma unroll
            for (int ki = 0; ki < KT; ++ki)
                code_out[(size_t)n*KK*FF + (size_t)(k0+ki)*FF + f] = xo[ki][ci];
        }
    }
}

// ---------------------------------------------------------------------------
// K4: ws[1] += sum over code1 of (1/(|code|+0.01))^2
__global__ __launch_bounds__(256) void k_wnorm(const float* __restrict__ code,
                                               float* __restrict__ ws) {
    __shared__ float red[256];
    size_t i0 = (size_t)blockIdx.x * 256 + threadIdx.x;
    size_t stride = (size_t)gridDim.x * 256;
    float s = 0.f;
    for (size_t i = i0; i < (size_t)CODE_SZ; i += stride) {
        float wn = 1.f / (fabsf(code[i]) + 0.01f);
        s += wn * wn;
    }
    red[threadIdx.x] = s;
    __syncthreads();
    for (int off = 128; off > 0; off >>= 1) {
        if (threadIdx.x < off) red[threadIdx.x] += red[threadIdx.x + off];
        __syncthreads();
    }
    if (threadIdx.x == 0) atomicAdd(&ws[1], red[0]);
}

// ---------------------------------------------------------------------------
// K5: reconst[n][t][f] = sum_k D[t][k] * code[n][k][f]
__global__ __launch_bounds__(256) void k_reconst(float* __restrict__ out) {
    __shared__ float Dl[TT*KK];
    __shared__ float cl[KK*FF];
    int n = blockIdx.x, tid = threadIdx.x;
    for (int e = tid; e < TT*KK; e += 256) Dl[e] = out[D_OFF + e];
    for (int e = tid; e < KK*FF; e += 256) cl[e] = out[(size_t)n*KK*FF + e];
    __syncthreads();
    for (int e = tid; e < TT*FF; e += 256) {
        int t = e / FF, f = e % FF;
        float s = 0.f;
        for (int k = 0; k < KK; ++k) s += Dl[t*KK + k] * cl[k*FF + f];
        out[R_OFF + (size_t)n*TT*FF + e] = s;
    }
}

// ---------------------------------------------------------------------------
extern "C" void kernel_launch(void* const* d_in, const int* in_sizes, int n_in,
                              void* d_out, int out_size, void* d_ws, size_t ws_size,
                              hipStream_t stream) {
    const float* x  = (const float*)d_in[0];
    const float* rr = (const float*)d_in[1];
    const float* th = (const float*)d_in[2];
    float* out = (float*)d_out;
    float* ws  = (float*)d_ws;
    float* ws_c = ws + WSC;

    hipLaunchKernelGGL(k_build,   dim3(1),   dim3(256), 0, stream, rr, th, out, ws);
    hipLaunchKernelGGL(k_dty,     dim3(NB),  dim3(256), 0, stream, x, out, ws, ws_c);
    hipLaunchKernelGGL(k_fista,   dim3(NB*FF/CB), dim3(256), 0, stream, ws + WSA, ws_c, ws, out, 0);
    hipLaunchKernelGGL(k_wnorm,   dim3(1024), dim3(256), 0, stream, out, ws);
    hipLaunchKernelGGL(k_fista,   dim3(NB*FF/CB), dim3(256), 0, stream, ws + WSA, ws_c, ws, out, 1);
    hipLaunchKernelGGL(k_reconst, dim3(NB),  dim3(256), 0, stream, out);
}

// Round 2
// 657.676 us; speedup vs baseline: 6.8733x; 6.8733x over previous
//
#include <hip/hip_runtime.h>
#include <math.h>

// Problem constants
#define NB   256      // batch N
#define TT   36       // T
#define FF   50       // F
#define PP   80       // npole
#define KK   161      // K = 1 + 2*npole
#define NITER 100
#define LAMB 0.1f

#define CODE_SZ (NB*KK*FF)          // 2,060,800
#define D_OFF   CODE_SZ
#define R_OFF   (CODE_SZ + TT*KK)

// ws layout (floats): [0]=Linv, [1]=wn^2 accumulator, [2..63] pad;
// then A1 image (D, 3 Mt x 6 Kt x 2 halves x 512 f16 = 18432 f16),
// then A2 image (D^T, 12 Mt x 2 Kt x 2 halves x 512 f16 = 24576 f16)
// total f16 = 43008 = 21504 floats
#define WSC (64 + 21504)            // c = Linv*DtY, [12800][KK]

typedef _Float16 half8 __attribute__((ext_vector_type(8)));
typedef float f32x4 __attribute__((ext_vector_type(4)));
#define MFMA16(A,B,C) __builtin_amdgcn_mfma_f32_16x16x32_f16(A,B,C,0,0,0)

// ---------------------------------------------------------------------------
// K1: build D -> d_out, L = ||DtD||_F, pack f16 hi/lo MFMA A-operand images
// for D (GEMM1 A) and D^T (GEMM2 A) into ws.
// A-frag layout (16x16x32): lane l holds A[m = l&15][k = (l>>4)*8 + i], i=0..7.
__global__ __launch_bounds__(256) void k_build(const float* __restrict__ rr,
                                               const float* __restrict__ th,
                                               float* __restrict__ out,
                                               float* __restrict__ ws) {
    __shared__ float Dl[TT*KK];
    __shared__ float red[256];
    int tid = threadIdx.x;
    for (int e = tid; e < TT*KK; e += 256) {
        int t = e / KK, k = e % KK;
        float v;
        if (k == 0) v = 1.f;
        else if (k <= PP) { int p = k - 1;     v = powf(rr[p], (float)t) * cosf((float)t * th[p]); }
        else             { int p = k - 1 - PP; v = powf(rr[p], (float)t) * sinf((float)t * th[p]); }
        Dl[e] = v;
        out[D_OFF + e] = v;
    }
    __syncthreads();
    float ssq = 0.f;
    for (int e = tid; e < KK*KK; e += 256) {
        int k1 = e / KK, k2 = e % KK;
        float s = 0.f;
        for (int t = 0; t < TT; ++t) s += Dl[t*KK + k1] * Dl[t*KK + k2];
        ssq += s * s;
    }
    red[tid] = ssq;
    __syncthreads();
    for (int off = 128; off > 0; off >>= 1) {
        if (tid < off) red[tid] += red[tid + off];
        __syncthreads();
    }
    if (tid == 0) { float linv = 1.f / sqrtf(red[0]); ws[0] = linv; ws[1] = 0.f; }
    __syncthreads();

    _Float16* a1 = (_Float16*)(ws + 64);
    _Float16* a2 = a1 + 18432;
    // A1: D tiles (M = t: 3 tiles of 16, K = j: 6 tiles of 32), UNSCALED
    for (int e = tid; e < 3*6*512; e += 256) {
        int fp = e & 511, mk = e >> 9;              // mk = mt*6 + kt
        int l = fp >> 3, i = fp & 7;
        int t = (mk / 6) * 16 + (l & 15);
        int j = (mk % 6) * 32 + ((l >> 4) << 3) + i;
        float v = (t < TT && j < KK) ? Dl[t*KK + j] : 0.f;
        _Float16 hi = (_Float16)v;
        _Float16 lo = (_Float16)(v - (float)hi);
        a1[(mk*2 + 0)*512 + fp] = hi;
        a1[(mk*2 + 1)*512 + fp] = lo;
    }
    // A2: D^T tiles (M = k: 12 tiles of 16, K = t: 2 tiles of 32), UNSCALED
    for (int e = tid; e < 12*2*512; e += 256) {
        int fp = e & 511, mk = e >> 9;              // mk = Mt2*2 + kt
        int l = fp >> 3, i = fp & 7;
        int kc = (mk >> 1) * 16 + (l & 15);
        int t  = (mk & 1) * 32 + ((l >> 4) << 3) + i;
        float v = (kc < KK && t < TT) ? Dl[t*KK + kc] : 0.f;
        _Float16 hi = (_Float16)v;
        _Float16 lo = (_Float16)(v - (float)hi);
        a2[(mk*2 + 0)*512 + fp] = hi;
        a2[(mk*2 + 1)*512 + fp] = lo;
    }
}

// ---------------------------------------------------------------------------
// K2: ws_c[col][k] = Linv * sum_t D[t][k] * x[n][t][f], col = n*FF + f
__global__ __launch_bounds__(256) void k_dty(const float* __restrict__ x,
                                             const float* __restrict__ out_d,
                                             const float* __restrict__ ws,
                                             float* __restrict__ ws_c) {
    __shared__ float Dl[TT*KK];
    __shared__ float xl[TT*FF];
    int n = blockIdx.x, tid = threadIdx.x;
    for (int e = tid; e < TT*KK; e += 256) Dl[e] = out_d[D_OFF + e];
    for (int e = tid; e < TT*FF; e += 256) xl[e] = x[n*TT*FF + e];
    __syncthreads();
    float linv = ws[0];
    for (int e = tid; e < KK*FF; e += 256) {
        int k = e / FF, f = e % FF;
        float s = 0.f;
        for (int t = 0; t < TT; ++t) s += Dl[t*KK + k] * xl[t*FF + f];
        ws_c[(size_t)(n*FF + f)*KK + k] = s * linv;
    }
}

// ---------------------------------------------------------------------------
// K3: 100 FISTA iterations via factorized MFMA: Ay = y - Linv * D^T (D y).
// Block = 768 threads (12 waves), 1 block per n (FF=50 cols, padded to 64).
// Wave w: GEMM1 combo (Mt1=w>>2 of 3, nt1=w&3 of 4); GEMM2 Mtile w (of 12).
// f16 split-precision: v = hi + lo; 3-term products; fp32 accumulate.
__global__ __launch_bounds__(768, 3) void k_fista(const float* __restrict__ ws,
                                                  const float* __restrict__ cgl,
                                                  float* __restrict__ code_out,
                                                  int phase) {
    __shared__ __align__(16) ushort A1s[18432];  // 36,864 B: [mt*6+kt][h][lane][8]
    __shared__ __align__(16) ushort Ys[24576];   // 49,152 B: [h][nt:4][kt:6][lane][8]
    __shared__ __align__(16) ushort Zs[8192];    // 16,384 B: [h][nt:4][kt:2][lane][8]
    int tid = threadIdx.x;
    {   // stage A1 image to LDS, zero y/z images (y0 = 0)
        const uint4* src = (const uint4*)(ws + 64);
        uint4* d1 = (uint4*)A1s;
        for (int e = tid; e < 2304; e += 768) d1[e] = src[e];
        uint4 z; z.x = z.y = z.z = z.w = 0u;
        uint4* dy = (uint4*)Ys;
        for (int e = tid; e < 3072; e += 768) dy[e] = z;
        uint4* dz = (uint4*)Zs;
        for (int e = tid; e < 1024; e += 768) dz[e] = z;
    }
    int w = tid >> 6, l = tid & 63;
    int cl = l & 15, q = l >> 4;
    int Mt1 = w >> 2, nt1 = w & 3;
    int b = blockIdx.x;                    // block b <-> n = b (C = FF = 50)
    float linv = ws[0];

    // GEMM2 A-frags (D^T) resident in registers: [kt][half]
    const _Float16* a2g = (const _Float16*)(ws + 64) + 18432;
    half8 a2[2][2];
    #pragma unroll
    for (int kt = 0; kt < 2; ++kt)
        #pragma unroll
        for (int h = 0; h < 2; ++h)
            a2[kt][h] = *(const half8*)(a2g + ((((w*2 + kt)*2 + h) << 9) + (l << 3)));

    // per-lane owned outputs: k = kb + r (r=0..3), c = nt*16 + cl (nt=0..3)
    int kb = w*16 + (q << 2);
    float cm[4][4], cp[4][4], xo[4][4], yo[4][4];
    {
        float wl0 = LAMB * linv;
        float fac = 0.f;
        if (phase) fac = (float)KK * LAMB * linv * rsqrtf(ws[1]);
        #pragma unroll
        for (int nt = 0; nt < 4; ++nt) {
            int c = nt*16 + cl;
            #pragma unroll
            for (int r = 0; r < 4; ++r) {
                int k = kb + r;
                float cv = 0.f, wl = 0.f;
                if (k < KK && c < FF) {
                    cv = cgl[(size_t)(b*FF + c)*KK + k];
                    if (phase) {
                        float prev = code_out[(size_t)b*KK*FF + k*FF + c];
                        wl = fac / (fabsf(prev) + 0.01f);
                    } else wl = wl0;
                }
                cm[nt][r] = cv - wl; cp[nt][r] = cv + wl;
                xo[nt][r] = 0.f;     yo[nt][r] = 0.f;
            }
        }
    }
    // epilogue B-frag write addressing (4 C/D rows per lane are k-contiguous -> b64)
    int kty = kb >> 5, kiny = kb & 31;
    int ybl = ((kiny >> 3) << 4) + cl, yib = kiny & 7;
    int ttb = Mt1*16 + (q << 2);
    int ktz = ttb >> 5, zin = ttb & 31;
    int zbl = ((zin >> 3) << 4) + cl, zib = zin & 7;

    __syncthreads();

    float t_old = 1.f;
    for (int it = 0; it < NITER; ++it) {
        // ---- GEMM1: z(Mt1, nt1) = D @ y, 6 Ktiles x 3 split-terms
        f32x4 za = {0.f,0.f,0.f,0.f}, zb = {0.f,0.f,0.f,0.f};
        #pragma unroll
        for (int kt = 0; kt < 6; ++kt) {
            half8 ah = *(const half8*)&A1s[((Mt1*6 + kt)*2 + 0)*512 + (l << 3)];
            half8 al = *(const half8*)&A1s[((Mt1*6 + kt)*2 + 1)*512 + (l << 3)];
            half8 bh = *(const half8*)&Ys[(((0*4 + nt1)*6 + kt) << 9) + (l << 3)];
            half8 bl = *(const half8*)&Ys[(((1*4 + nt1)*6 + kt) << 9) + (l << 3)];
            if (kt & 1) { zb = MFMA16(ah, bh, zb); zb = MFMA16(ah, bl, zb); zb = MFMA16(al, bh, zb); }
            else        { za = MFMA16(ah, bh, za); za = MFMA16(ah, bl, za); za = MFMA16(al, bh, za); }
        }
        f32x4 zz = za + zb;
        {   // split z to f16 hi/lo, write into GEMM2 B-frag image
            union { unsigned long long u; _Float16 h[4]; } ph, pl;
            #pragma unroll
            for (int r = 0; r < 4; ++r) {
                float v = zz[r];
                _Float16 hi = (_Float16)v;
                ph.h[r] = hi; pl.h[r] = (_Float16)(v - (float)hi);
            }
            *(unsigned long long*)&Zs[(((0*4 + nt1)*2 + ktz) << 9) + (zbl << 3) + zib] = ph.u;
            *(unsigned long long*)&Zs[(((1*4 + nt1)*2 + ktz) << 9) + (zbl << 3) + zib] = pl.u;
        }
        __syncthreads();

        // ---- GEMM2: w(Mt2 = w, all nt) = D^T @ z, A-frags in registers
        f32x4 acc[4];
        #pragma unroll
        for (int nt = 0; nt < 4; ++nt) { acc[nt].x=0.f; acc[nt].y=0.f; acc[nt].z=0.f; acc[nt].w=0.f; }
        #pragma unroll
        for (int nt = 0; nt < 4; ++nt) {
            #pragma unroll
            for (int kt = 0; kt < 2; ++kt) {
                half8 bh = *(const half8*)&Zs[(((0*4 + nt)*2 + kt) << 9) + (l << 3)];
                half8 bl = *(const half8*)&Zs[(((1*4 + nt)*2 + kt) << 9) + (l << 3)];
                acc[nt] = MFMA16(a2[kt][0], bh, acc[nt]);
                acc[nt] = MFMA16(a2[kt][0], bl, acc[nt]);
                acc[nt] = MFMA16(a2[kt][1], bh, acc[nt]);
            }
        }
        // ---- epilogue: soft-threshold + momentum, rebuild y image
        float t_new = 0.5f * (1.f + sqrtf(1.f + 4.f*t_old*t_old));
        float beta = (t_old - 1.f) / t_new;
        t_old = t_new;
        #pragma unroll
        for (int nt = 0; nt < 4; ++nt) {
            union { unsigned long long u; _Float16 h[4]; } ph, pl;
            #pragma unroll
            for (int r = 0; r < 4; ++r) {
                float ay = fmaf(-linv, acc[nt][r], yo[nt][r]);   // y - Linv*w
                float xn = fmaxf(0.f, ay + cm[nt][r]) + fminf(0.f, ay + cp[nt][r]);
                float yn = fmaf(beta, xn - xo[nt][r], xn);
                xo[nt][r] = xn; yo[nt][r] = yn;
                _Float16 hi = (_Float16)yn;
                ph.h[r] = hi; pl.h[r] = (_Float16)(yn - (float)hi);
            }
            *(unsigned long long*)&Ys[(((0*4 + nt)*6 + kty) << 9) + (ybl << 3) + yib] = ph.u;
            *(unsigned long long*)&Ys[(((1*4 + nt)*6 + kty) << 9) + (ybl << 3) + yib] = pl.u;
        }
        __syncthreads();
    }
    // store x_final (guards: pad rows/cols never stored)
    #pragma unroll
    for (int nt = 0; nt < 4; ++nt) {
        int c = nt*16 + cl;
        #pragma unroll
        for (int r = 0; r < 4; ++r) {
            int k = kb + r;
            if (k < KK && c < FF)
                code_out[(size_t)b*KK*FF + k*FF + c] = xo[nt][r];
        }
    }
}

// ---------------------------------------------------------------------------
// K4: ws[1] += sum over code of (1/(|code|+0.01))^2
__global__ __launch_bounds__(256) void k_wnorm(const float* __restrict__ code,
                                               float* __restrict__ ws) {
    __shared__ float red[256];
    size_t i0 = (size_t)blockIdx.x * 256 + threadIdx.x;
    size_t stride = (size_t)gridDim.x * 256;
    float s = 0.f;
    for (size_t i = i0; i < (size_t)CODE_SZ; i += stride) {
        float wn = 1.f / (fabsf(code[i]) + 0.01f);
        s += wn * wn;
    }
    red[threadIdx.x] = s;
    __syncthreads();
    for (int off = 128; off > 0; off >>= 1) {
        if (threadIdx.x < off) red[threadIdx.x] += red[threadIdx.x + off];
        __syncthreads();
    }
    if (threadIdx.x == 0) atomicAdd(&ws[1], red[0]);
}

// ---------------------------------------------------------------------------
// K5: reconst[n][t][f] = sum_k D[t][k] * code[n][k][f]
__global__ __launch_bounds__(256) void k_reconst(float* __restrict__ out) {
    __shared__ float Dl[TT*KK];
    __shared__ float cl[KK*FF];
    int n = blockIdx.x, tid = threadIdx.x;
    for (int e = tid; e < TT*KK; e += 256) Dl[e] = out[D_OFF + e];
    for (int e = tid; e < KK*FF; e += 256) cl[e] = out[(size_t)n*KK*FF + e];
    __syncthreads();
    for (int e = tid; e < TT*FF; e += 256) {
        int t = e / FF, f = e % FF;
        float s = 0.f;
        for (int k = 0; k < KK; ++k) s += Dl[t*KK + k] * cl[k*FF + f];
        out[R_OFF + (size_t)n*TT*FF + e] = s;
    }
}

// ---------------------------------------------------------------------------
extern "C" void kernel_launch(void* const* d_in, const int* in_sizes, int n_in,
                              void* d_out, int out_size, void* d_ws, size_t ws_size,
                              hipStream_t stream) {
    const float* x  = (const float*)d_in[0];
    const float* rr = (const float*)d_in[1];
    const float* th = (const float*)d_in[2];
    float* out = (float*)d_out;
    float* ws  = (float*)d_ws;
    float* ws_c = ws + WSC;

    hipLaunchKernelGGL(k_build,   dim3(1),   dim3(256), 0, stream, rr, th, out, ws);
    hipLaunchKernelGGL(k_dty,     dim3(NB),  dim3(256), 0, stream, x, out, ws, ws_c);
    hipLaunchKernelGGL(k_fista,   dim3(NB),  dim3(768), 0, stream, ws, ws_c, out, 0);
    hipLaunchKernelGGL(k_wnorm,   dim3(1024), dim3(256), 0, stream, out, ws);
    hipLaunchKernelGGL(k_fista,   dim3(NB),  dim3(768), 0, stream, ws, ws_c, out, 1);
    hipLaunchKernelGGL(k_reconst, dim3(NB),  dim3(256), 0, stream, out);
}

// Round 3
// 543.567 us; speedup vs baseline: 8.3162x; 1.2099x over previous
//
#include <hip/hip_runtime.h>
#include <math.h>

// Problem constants
#define NB   256
#define TT   36
#define FF   50
#define PP   80
#define KK   161
#define NITER 100
#define LAMB 0.1f

#define CODE_SZ (NB*KK*FF)          // 2,060,800
#define D_OFF   CODE_SZ
#define R_OFF   (CODE_SZ + TT*KK)
#define NCOL    (NB*FF)             // 12800

// ws float layout:
// [1] = wn^2 accumulator (zeroed by k_build blk0, atomicAdd by k_wnorm)
// [16..79] = ssq partials (64 blocks of k_build)
// [WSA1..] A1 image: [Mt1:3][kt:6][h:2][512] f16  (9216 floats)
// [WSA2..] A2 image: [Mt2:6][kt:3][h:2][512] f16  (9216 floats)
// [WSC..]  raw DtY, transposed: [k:KK][col:NCOL]
#define WSA1 128
#define WSA2 (128 + 9216)
#define WSC  (128 + 18432)

typedef _Float16 half8 __attribute__((ext_vector_type(8)));
typedef float f32x4  __attribute__((ext_vector_type(4)));
typedef float f32x16 __attribute__((ext_vector_type(16)));
#define MFMA_16(A,B,C) __builtin_amdgcn_mfma_f32_16x16x32_f16(A,B,C,0,0,0)
#define MFMA_32(A,B,C) __builtin_amdgcn_mfma_f32_32x32x16_f16(A,B,C,0,0,0)

// ---------------------------------------------------------------------------
// K1 (grid 64): build D (blk0 -> d_out), ssq partials -> ws[16+b],
// pack f16 hi/lo A-operand images for D (GEMM1, 16x16x32) and D^T (GEMM2,
// 32x32x16) into ws. All unscaled (Linv applied in k_fista).
__global__ __launch_bounds__(256) void k_build(const float* __restrict__ rr,
                                               const float* __restrict__ th,
                                               float* __restrict__ out,
                                               float* __restrict__ ws) {
    __shared__ float Dl[TT*KK];
    __shared__ float red[256];
    int tid = threadIdx.x, b = blockIdx.x;
    for (int e = tid; e < TT*KK; e += 256) {
        int t = e / KK, k = e % KK;
        float v;
        if (k == 0) v = 1.f;
        else if (k <= PP) { int p = k - 1;     v = powf(rr[p], (float)t) * cosf((float)t * th[p]); }
        else              { int p = k - 1 - PP; v = powf(rr[p], (float)t) * sinf((float)t * th[p]); }
        Dl[e] = v;
        if (b == 0) out[D_OFF + e] = v;
    }
    __syncthreads();
    float ssq = 0.f;
    for (int p = b*256 + tid; p < KK*KK; p += 64*256) {
        int k1 = p / KK, k2 = p % KK;
        float s = 0.f;
        for (int t = 0; t < TT; ++t) s += Dl[t*KK + k1] * Dl[t*KK + k2];
        ssq += s * s;
    }
    red[tid] = ssq;
    __syncthreads();
    for (int off = 128; off > 0; off >>= 1) {
        if (tid < off) red[tid] += red[tid + off];
        __syncthreads();
    }
    if (tid == 0) { ws[16 + b] = red[0]; if (b == 0) ws[1] = 0.f; }

    // A1: lane l holds A[m=l&15][k=8*(l>>4)+i] per 16x16x32 tile
    _Float16* a1 = (_Float16*)(ws + WSA1);
    for (int e = b*256 + tid; e < 3*6*2*512; e += 64*256) {
        int fp = e & 511, r = e >> 9;       // r = (Mt1*6+kt)*2 + h
        int h = r & 1, mk = r >> 1;
        int l = fp >> 3, i = fp & 7;
        int t = (mk / 6) * 16 + (l & 15);
        int j = (mk % 6) * 32 + ((l >> 4) << 3) + i;
        float v = (t < TT && j < KK) ? Dl[t*KK + j] : 0.f;
        _Float16 hi = (_Float16)v;
        a1[e] = h ? (_Float16)(v - (float)hi) : hi;
    }
    // A2 (D^T): lane l holds A[m=l&31][k=8*(l>>5)+i] per 32x32x16 tile
    _Float16* a2 = (_Float16*)(ws + WSA2);
    for (int e = b*256 + tid; e < 6*3*2*512; e += 64*256) {
        int fp = e & 511, r = e >> 9;       // r = (Mt2*3+kt)*2 + h
        int h = r & 1, mk = r >> 1;
        int l = fp >> 3, i = fp & 7;
        int m = (mk / 3) * 32 + (l & 31);               // atom index (row of D^T)
        int t = (mk % 3) * 16 + ((l >> 5) << 3) + i;    // k-dim = time
        float v = (m < KK && t < TT) ? Dl[t*KK + m] : 0.f;
        _Float16 hi = (_Float16)v;
        a2[e] = h ? (_Float16)(v - (float)hi) : hi;
    }
}

// ---------------------------------------------------------------------------
// K2: raw DtY transposed: ws_c[k][n*FF+f] = sum_t D[t][k] * x[n][t][f]
__global__ __launch_bounds__(256) void k_dty(const float* __restrict__ x,
                                             const float* __restrict__ out_d,
                                             float* __restrict__ ws_c) {
    __shared__ float Dl[TT*KK];
    __shared__ float xl[TT*FF];
    int n = blockIdx.x, tid = threadIdx.x;
    for (int e = tid; e < TT*KK; e += 256) Dl[e] = out_d[D_OFF + e];
    for (int e = tid; e < TT*FF; e += 256) xl[e] = x[n*TT*FF + e];
    __syncthreads();
    for (int e = tid; e < KK*FF; e += 256) {
        int k = e / FF, f = e % FF;
        float s = 0.f;
        for (int t = 0; t < TT; ++t) s += Dl[t*KK + k] * xl[t*FF + f];
        ws_c[(size_t)k*NCOL + n*FF + f] = s;
    }
}

// ---------------------------------------------------------------------------
// K3: 100 FISTA iterations, factorized: Ay = y - Linv * D^T (D y).
// 768 threads (12 waves), 1 block per batch n. GEMM1 (z = D y): 16x16x32,
// wave = (Mt1 = w>>2 of 3, nt1 = w&3 of 4), A-frags in VGPRs.
// GEMM2 (w = D^T z): 32x32x16, wave = (Mt2 = w>>1 of 6, nh = w&1), A in VGPRs.
// f16 split (hi+lo), 3-term products, fp32 accumulate.
__global__ __launch_bounds__(768, 3) void k_fista(const float* __restrict__ ws,
                                                  float* __restrict__ code_out,
                                                  int phase) {
    __shared__ __align__(16) ushort Ys[2*4*6*512];   // 49,152 B: [h][nt16:4][kt32:6][512]
    __shared__ __align__(16) ushort Zs[2*2*3*512];   // 12,288 B: [h][nh:2][kt16:3][512]
    int tid = threadIdx.x;
    {   // y0 = 0
        uint4 z; z.x = z.y = z.z = z.w = 0u;
        uint4* dy = (uint4*)Ys;
        for (int e = tid; e < 3072; e += 768) dy[e] = z;
    }
    int w = tid >> 6, l = tid & 63;
    float ssum = 0.f;
    #pragma unroll
    for (int i = 0; i < 64; ++i) ssum += ws[16 + i];
    float linv = rsqrtf(ssum);

    int Mt1 = w >> 2, nt1 = w & 3;
    int Mt2 = w >> 1, nh  = w & 1;
    const _Float16* a1g = (const _Float16*)(ws + WSA1);
    const _Float16* a2g = (const _Float16*)(ws + WSA2);
    half8 a1[6][2];
    #pragma unroll
    for (int kt = 0; kt < 6; ++kt)
        #pragma unroll
        for (int h = 0; h < 2; ++h)
            a1[kt][h] = *(const half8*)(a1g + ((((Mt1*6 + kt)*2 + h) << 9) + (l << 3)));
    half8 a2[3][2];
    #pragma unroll
    for (int kt = 0; kt < 3; ++kt)
        #pragma unroll
        for (int h = 0; h < 2; ++h)
            a2[kt][h] = *(const half8*)(a2g + ((((Mt2*3 + kt)*2 + h) << 9) + (l << 3)));

    // lane-owned outputs (GEMM2 32x32 C/D): col c = nh*32+(l&31),
    // k = Mt2*32 + 8g + 4*(l>>5) + j  (quad g = reg>>2, j = reg&3)
    int nloc = l & 31, c = nh*32 + nloc, s5 = l >> 5;
    int b = blockIdx.x;
    const float* cg = ws + WSC;
    float cm[4][4], cp[4][4], xo[4][4], yo[4][4];
    {
        float wl0 = LAMB * linv;
        float fac = 0.f;
        if (phase) fac = (float)KK * LAMB * linv * rsqrtf(ws[1]);
        #pragma unroll
        for (int g = 0; g < 4; ++g) {
            int k0 = Mt2*32 + 8*g + 4*s5;
            #pragma unroll
            for (int j = 0; j < 4; ++j) {
                int k = k0 + j;
                float cv = 0.f, wl = 0.f;
                if (k < KK && c < FF) {
                    cv = linv * cg[(size_t)k*NCOL + b*FF + c];
                    if (phase) {
                        float prev = code_out[(size_t)b*KK*FF + k*FF + c];
                        wl = fac / (fabsf(prev) + 0.01f);
                    } else wl = wl0;
                }
                cm[g][j] = cv - wl; cp[g][j] = cv + wl;
                xo[g][j] = 0.f;     yo[g][j] = 0.f;
            }
        }
    }
    int q = l >> 4, cl = l & 15;
    int zlofs = (((q >> 1)*32 + (nt1 & 1)*16 + cl) << 3) + ((q & 1) << 2);
    int znh = nt1 >> 1;
    int nt16 = nh*2 + (nloc >> 4);
    __syncthreads();

    float t_old = 1.f;
    for (int it = 0; it < NITER; ++it) {
        // ---- GEMM1: z(Mt1, nt1) = D @ y
        f32x4 za = {0.f,0.f,0.f,0.f}, zb = {0.f,0.f,0.f,0.f};
        #pragma unroll
        for (int kt = 0; kt < 6; ++kt) {
            half8 bh = *(const half8*)&Ys[(((0*4 + nt1)*6 + kt) << 9) + (l << 3)];
            half8 bl = *(const half8*)&Ys[(((1*4 + nt1)*6 + kt) << 9) + (l << 3)];
            if (kt & 1) { zb = MFMA_16(a1[kt][0], bh, zb); zb = MFMA_16(a1[kt][0], bl, zb); zb = MFMA_16(a1[kt][1], bh, zb); }
            else        { za = MFMA_16(a1[kt][0], bh, za); za = MFMA_16(a1[kt][0], bl, za); za = MFMA_16(a1[kt][1], bh, za); }
        }
        f32x4 zz = za + zb;
        {   // write z into GEMM2 B-frag image (16x16 C/D quad -> b64 hi + b64 lo)
            union { unsigned long long u; _Float16 hh[4]; } ph, pl;
            #pragma unroll
            for (int r = 0; r < 4; ++r) {
                float v = zz[r];
                _Float16 hi = (_Float16)v;
                ph.hh[r] = hi; pl.hh[r] = (_Float16)(v - (float)hi);
            }
            *(unsigned long long*)&Zs[(((0*2 + znh)*3 + Mt1) << 9) + zlofs] = ph.u;
            *(unsigned long long*)&Zs[(((1*2 + znh)*3 + Mt1) << 9) + zlofs] = pl.u;
        }
        __syncthreads();

        // ---- GEMM2: acc(Mt2, nh) = D^T @ z (single acc chain to cap VGPRs)
        f32x16 acc;
        #pragma unroll
        for (int r = 0; r < 16; ++r) acc[r] = 0.f;
        #pragma unroll
        for (int kt = 0; kt < 3; ++kt) {
            half8 bh = *(const half8*)&Zs[(((0*2 + nh)*3 + kt) << 9) + (l << 3)];
            half8 bl = *(const half8*)&Zs[(((1*2 + nh)*3 + kt) << 9) + (l << 3)];
            acc = MFMA_32(a2[kt][0], bh, acc);
            acc = MFMA_32(a2[kt][0], bl, acc);
            acc = MFMA_32(a2[kt][1], bh, acc);
        }
        // ---- epilogue: shrink + momentum, rebuild y image
        float t_new = 0.5f * (1.f + sqrtf(1.f + 4.f*t_old*t_old));
        float beta = (t_old - 1.f) / t_new;
        t_old = t_new;
        #pragma unroll
        for (int g = 0; g < 4; ++g) {
            union { unsigned long long u; _Float16 hh[4]; } yh, yl;
            #pragma unroll
            for (int j = 0; j < 4; ++j) {
                float ay = fmaf(-linv, acc[g*4 + j], yo[g][j]);
                float xn = fmaxf(0.f, ay + cm[g][j]) + fminf(0.f, ay + cp[g][j]);
                float yn = fmaf(beta, xn - xo[g][j], xn);
                xo[g][j] = xn; yo[g][j] = yn;
                _Float16 hi = (_Float16)yn;
                yh.hh[j] = hi; yl.hh[j] = (_Float16)(yn - (float)hi);
            }
            int yofs = (((g*16 + cl) << 3)) + (s5 << 2);
            *(unsigned long long*)&Ys[(((0*4 + nt16)*6 + Mt2) << 9) + yofs] = yh.u;
            *(unsigned long long*)&Ys[(((1*4 + nt16)*6 + Mt2) << 9) + yofs] = yl.u;
        }
        __syncthreads();
    }
    #pragma unroll
    for (int g = 0; g < 4; ++g) {
        int k0 = Mt2*32 + 8*g + 4*s5;
        #pragma unroll
        for (int j = 0; j < 4; ++j) {
            int k = k0 + j;
            if (k < KK && c < FF)
                code_out[(size_t)b*KK*FF + k*FF + c] = xo[g][j];
        }
    }
}

// ---------------------------------------------------------------------------
// K4: ws[1] += sum over code of (1/(|code|+0.01))^2
__global__ __launch_bounds__(256) void k_wnorm(const float* __restrict__ code,
                                               float* __restrict__ ws) {
    __shared__ float red[256];
    size_t i0 = (size_t)blockIdx.x * 256 + threadIdx.x;
    size_t stride = (size_t)gridDim.x * 256;
    float s = 0.f;
    for (size_t i = i0; i < (size_t)CODE_SZ; i += stride) {
        float wn = 1.f / (fabsf(code[i]) + 0.01f);
        s += wn * wn;
    }
    red[threadIdx.x] = s;
    __syncthreads();
    for (int off = 128; off > 0; off >>= 1) {
        if (threadIdx.x < off) red[threadIdx.x] += red[threadIdx.x + off];
        __syncthreads();
    }
    if (threadIdx.x == 0) atomicAdd(&ws[1], red[0]);
}

// ---------------------------------------------------------------------------
// K5: reconst[n][t][f] = sum_k D[t][k] * code[n][k][f]
__global__ __launch_bounds__(256) void k_reconst(float* __restrict__ out) {
    __shared__ float Dl[TT*KK];
    __shared__ float cl[KK*FF];
    int n = blockIdx.x, tid = threadIdx.x;
    for (int e = tid; e < TT*KK; e += 256) Dl[e] = out[D_OFF + e];
    for (int e = tid; e < KK*FF; e += 256) cl[e] = out[(size_t)n*KK*FF + e];
    __syncthreads();
    for (int e = tid; e < TT*FF; e += 256) {
        int t = e / FF, f = e % FF;
        float s = 0.f;
        for (int k = 0; k < KK; ++k) s += Dl[t*KK + k] * cl[k*FF + f];
        out[R_OFF + (size_t)n*TT*FF + e] = s;
    }
}

// ---------------------------------------------------------------------------
extern "C" void kernel_launch(void* const* d_in, const int* in_sizes, int n_in,
                              void* d_out, int out_size, void* d_ws, size_t ws_size,
                              hipStream_t stream) {
    const float* x  = (const float*)d_in[0];
    const float* rr = (const float*)d_in[1];
    const float* th = (const float*)d_in[2];
    float* out = (float*)d_out;
    float* ws  = (float*)d_ws;
    float* ws_c = ws + WSC;

    hipLaunchKernelGGL(k_build,   dim3(64),   dim3(256), 0, stream, rr, th, out, ws);
    hipLaunchKernelGGL(k_dty,     dim3(NB),   dim3(256), 0, stream, x, out, ws_c);
    hipLaunchKernelGGL(k_fista,   dim3(NB),   dim3(768), 0, stream, ws, out, 0);
    hipLaunchKernelGGL(k_wnorm,   dim3(1024), dim3(256), 0, stream, out, ws);
    hipLaunchKernelGGL(k_fista,   dim3(NB),   dim3(768), 0, stream, ws, out, 1);
    hipLaunchKernelGGL(k_reconst, dim3(NB),   dim3(256), 0, stream, out);
}